// Round 7
// baseline (6406.090 us; speedup 1.0000x reference)
//
#include <hip/hip_runtime.h>
#include <stdint.h>

// ---------------------------------------------------------------------------
// 2-layer LSTM (T=256, B=256, F=128, H=1024) for MI355X (gfx950).
// R7: h exchange via SYSTEM-scope (sc0+sc1) relaxed atomics -> LLC is the
// coherence point; correct for ANY workgroup->XCD mapping. No fences, no
// cache invalidation, no co-XCD probe. Read-only streams (x, xw, weights)
// stay plain and L2-cached. x/xw fragments for step t+1 prefetched before
// the barrier. Per-group (32-WG) monotonic barrier, relaxed agent atomics.
// ---------------------------------------------------------------------------

typedef __bf16 bf16x8 __attribute__((ext_vector_type(8)));
typedef float  f32x4  __attribute__((ext_vector_type(4)));
typedef unsigned short ushort8v __attribute__((ext_vector_type(8)));
typedef unsigned int   uint4v   __attribute__((ext_vector_type(4)));
typedef __attribute__((address_space(1))) unsigned int as1_u32;
typedef __attribute__((address_space(3))) unsigned int as3_u32;

#define T_STEPS 256
#define BATCH   256
#define HDIM    1024
#define GDIM    4096
#define FDIM    128
#define AS_STRIDE 2080   // bytes/row in LDS h slab

static __device__ __forceinline__ float bf2f(unsigned short u) {
  union { unsigned int i; float f; } v; v.i = ((unsigned int)u) << 16; return v.f;
}
static __device__ __forceinline__ unsigned short f2bf(float f) {
  return __builtin_bit_cast(unsigned short, (__bf16)f);
}
static __device__ __forceinline__ float sigm(float x) { return 1.f / (1.f + __expf(-x)); }
static __device__ __forceinline__ float tanh_f(float x) { return 2.f / (1.f + __expf(-2.f * x)) - 1.f; }

// system-scope relaxed 8B load (sc0+sc1: bypass L1/L2, read LLC)
static __device__ __forceinline__ unsigned long long ld_sys_u64(const void* p) {
  return __hip_atomic_load((const unsigned long long*)p, __ATOMIC_RELAXED, __HIP_MEMORY_SCOPE_SYSTEM);
}
// system-scope relaxed 4B store (write-through to LLC)
static __device__ __forceinline__ void st_sys_u32(void* p, unsigned int v) {
  __hip_atomic_store((unsigned int*)p, v, __ATOMIC_RELAXED, __HIP_MEMORY_SCOPE_SYSTEM);
}

__global__ void conv_bf16(const float* __restrict__ s, unsigned short* __restrict__ d, int n) {
  int i = blockIdx.x * 256 + threadIdx.x;
  if (i < n) d[i] = f2bf(s[i]);
}

__global__ void diag_kernel(float* out, int n, float v) {
  int i = blockIdx.x * 256 + threadIdx.x;
  if (i < n) out[i] = v;
}

// ---------------- per-group (32-WG, same mi) monotonic barrier ---------------
// gbar region 512B: [0]=arrival counter, [64](+256B)=generation. Relaxed
// agent-scope atomics (LLC-coherent). Data ordering: producer h stores are
// system-scope and drained by the vmcnt(0) implicit in __syncthreads before
// the arrival atomic issues; consumers read h with system-scope loads after
// observing gen, so they read the LLC (no stale L2/L1 possible).
__device__ __forceinline__ void grp_barrier(unsigned int* gbar, unsigned int target) {
  __syncthreads();
  if (threadIdx.x == 0) {
    unsigned int my = __hip_atomic_fetch_add(&gbar[0], 1u, __ATOMIC_RELAXED, __HIP_MEMORY_SCOPE_AGENT);
    if ((my & 31u) == 31u)
      __hip_atomic_fetch_add(&gbar[64], 1u, __ATOMIC_RELAXED, __HIP_MEMORY_SCOPE_AGENT);
    for (unsigned int it = 0; it < (1u << 15); ++it) {
      unsigned int g = __hip_atomic_load(&gbar[64], __ATOMIC_RELAXED, __HIP_MEMORY_SCOPE_AGENT);
      if ((int)(g - target) >= 0) break;
      __builtin_amdgcn_s_sleep(1);
    }
  }
  __syncthreads();
}

// --------------------------- gemm_bt: C = A @ B^T ---------------------------
__global__ __launch_bounds__(256) void gemm_bt_xw(
    const unsigned short* __restrict__ A,
    const unsigned short* __restrict__ B,
    unsigned short* __restrict__ xw,
    int K)
{
  const int tid = threadIdx.x, lane = tid & 63, w = tid >> 6;
  const int m0 = blockIdx.x * 128;
  const int n0 = blockIdx.y * 128;
  __shared__ unsigned short As[128 * 64];
  __shared__ unsigned short Bs[128 * 64];
  const int mrow0 = (w & 1) * 64, ncol0 = (w >> 1) * 64;
  const int quad = lane >> 4;

  f32x4 acc[4][4];
  #pragma unroll
  for (int i = 0; i < 4; ++i)
    #pragma unroll
    for (int j = 0; j < 4; ++j) acc[i][j] = f32x4{0.f, 0.f, 0.f, 0.f};

  const int kiter = K >> 6;
  for (int ki = 0; ki < kiter; ++ki) {
    const int k0 = ki * 64;
    __syncthreads();
    #pragma unroll
    for (int i = 0; i < 4; ++i) {
      int obase = (w * 4 + i) * 1024;
      int o = obase + lane * 16;
      int row = o >> 7; int kb = o & 127;
      const char* ga = (const char*)A + ((size_t)(m0 + row) * K + k0) * 2 + kb;
      const char* gb = (const char*)B + ((size_t)(n0 + row) * K + k0) * 2 + kb;
      __builtin_amdgcn_global_load_lds((const as1_u32*)ga, (as3_u32*)((char*)As + obase), 16, 0, 0);
      __builtin_amdgcn_global_load_lds((const as1_u32*)gb, (as3_u32*)((char*)Bs + obase), 16, 0, 0);
    }
    __syncthreads();
    #pragma unroll
    for (int kk = 0; kk < 2; ++kk) {
      bf16x8 af[4], bfr[4];
      #pragma unroll
      for (int mt = 0; mt < 4; ++mt)
        af[mt] = *(const bf16x8*)(As + (mrow0 + mt * 16 + (lane & 15)) * 64 + kk * 32 + quad * 8);
      #pragma unroll
      for (int nt = 0; nt < 4; ++nt)
        bfr[nt] = *(const bf16x8*)(Bs + (ncol0 + nt * 16 + (lane & 15)) * 64 + kk * 32 + quad * 8);
      #pragma unroll
      for (int mt = 0; mt < 4; ++mt)
        #pragma unroll
        for (int nt = 0; nt < 4; ++nt)
          acc[mt][nt] = __builtin_amdgcn_mfma_f32_16x16x32_bf16(af[mt], bfr[nt], acc[mt][nt], 0, 0, 0);
    }
  }
  #pragma unroll
  for (int mt = 0; mt < 4; ++mt) {
    int m = m0 + mrow0 + mt * 16 + quad * 4;
    int tl = m >> 8, b = m & 255;
    #pragma unroll
    for (int nt = 0; nt < 4; ++nt) {
      int col = n0 + ncol0 + nt * 16 + (lane & 15);
      unsigned long long v;
      unsigned short* pv = (unsigned short*)&v;
      pv[0] = f2bf(acc[mt][nt][0]); pv[1] = f2bf(acc[mt][nt][1]);
      pv[2] = f2bf(acc[mt][nt][2]); pv[3] = f2bf(acc[mt][nt][3]);
      *(unsigned long long*)(xw + ((size_t)tl * GDIM + col) * BATCH + b) = v;
    }
  }
}

// --------------------------- layer 0: fused persistent chunk -----------------
// 256 WGs x 256 thr. WG (mi=wg&7, ni=wg>>3): rows [32mi,+32), cols [32ni,+32).
// Wave g = gate g; W_hh0 + W_ih0 fragments resident in VGPRs. h slab staged
// to LDS via system-scope 8B loads (LLC). h written via system-scope u32.
__global__ __launch_bounds__(256, 1) void lstm_layer0_kernel(
    const unsigned short* __restrict__ xbf,  // (T,B,F) bf16
    const float* __restrict__ Wih,
    const float* __restrict__ Whh,
    const float* __restrict__ bih,
    const float* __restrict__ bhh,
    unsigned short* __restrict__ slab,       // (ch_len+1, B, H)
    float* __restrict__ cstate,
    int t0, int ch_len, unsigned int gen_base,
    float* __restrict__ dout_h,
    float* __restrict__ dout_c,
    unsigned int* __restrict__ bar)
{
  const int tid = threadIdx.x, lane = tid & 63, wv = tid >> 6;
  const int quad = lane >> 4;
  const int wg = blockIdx.x;
  const int mi = wg & 7, ni = wg >> 3;
  const int r0 = mi * 32, hc0 = ni * 32;
  unsigned int* gbar = bar + mi * 128;   // 512B per group

  __shared__ unsigned short As[32 * (AS_STRIDE / 2)];
  __shared__ float gbuf[4][32][36];

  bf16x8 whh[2][32];
  #pragma unroll
  for (int nt = 0; nt < 2; ++nt) {
    const float* wrow = Whh + (size_t)(wv * HDIM + hc0 + nt * 16 + (lane & 15)) * HDIM + quad * 8;
    #pragma unroll
    for (int kk = 0; kk < 32; ++kk) {
      f32x4 f0 = *(const f32x4*)(wrow + kk * 32);
      f32x4 f1 = *(const f32x4*)(wrow + kk * 32 + 4);
      bf16x8 r;
      r[0] = (__bf16)f0[0]; r[1] = (__bf16)f0[1]; r[2] = (__bf16)f0[2]; r[3] = (__bf16)f0[3];
      r[4] = (__bf16)f1[0]; r[5] = (__bf16)f1[1]; r[6] = (__bf16)f1[2]; r[7] = (__bf16)f1[3];
      whh[nt][kk] = r;
    }
  }
  bf16x8 wih[2][4];
  #pragma unroll
  for (int nt = 0; nt < 2; ++nt) {
    const float* wrow = Wih + (size_t)(wv * HDIM + hc0 + nt * 16 + (lane & 15)) * FDIM + quad * 8;
    #pragma unroll
    for (int kk = 0; kk < 4; ++kk) {
      f32x4 f0 = *(const f32x4*)(wrow + kk * 32);
      f32x4 f1 = *(const f32x4*)(wrow + kk * 32 + 4);
      bf16x8 r;
      r[0] = (__bf16)f0[0]; r[1] = (__bf16)f0[1]; r[2] = (__bf16)f0[2]; r[3] = (__bf16)f0[3];
      r[4] = (__bf16)f1[0]; r[5] = (__bf16)f1[1]; r[6] = (__bf16)f1[2]; r[7] = (__bf16)f1[3];
      wih[nt][kk] = r;
    }
  }

  // pointwise ownership: thread -> cols {c2,c2+1}, rows {r2,r2+1}
  const int c2 = (tid & 15) * 2, rr2 = (tid >> 4) * 2;
  float bias[4][2];
  #pragma unroll
  for (int g = 0; g < 4; ++g)
    #pragma unroll
    for (int cc = 0; cc < 2; ++cc)
      bias[g][cc] = bih[g * HDIM + hc0 + c2 + cc] + bhh[g * HDIM + hc0 + c2 + cc];

  float c[2][2];
  #pragma unroll
  for (int rr = 0; rr < 2; ++rr)
    #pragma unroll
    for (int cc = 0; cc < 2; ++cc)
      c[rr][cc] = (t0 == 0) ? 0.f
                : cstate[(size_t)(r0 + rr2 + rr) * HDIM + hc0 + c2 + cc];

  // prefetch x fragments for first step
  bf16x8 xfrag[4][2];
  #pragma unroll
  for (int j = 0; j < 4; ++j)
    #pragma unroll
    for (int mt = 0; mt < 2; ++mt)
      xfrag[j][mt] = *(const bf16x8*)(xbf + (size_t)(t0 * BATCH + r0 + mt * 16 + (lane & 15)) * FDIM + j * 32 + quad * 8);

  const int tend = t0 + ch_len;
  #pragma unroll 1
  for (int t = t0; t < tend; ++t) {
    f32x4 acc[2][2];
    #pragma unroll
    for (int mt = 0; mt < 2; ++mt)
      #pragma unroll
      for (int nt = 0; nt < 2; ++nt) acc[mt][nt] = f32x4{0.f, 0.f, 0.f, 0.f};

    // x projection from prefetched fragments
    #pragma unroll
    for (int j = 0; j < 4; ++j)
      #pragma unroll
      for (int mt = 0; mt < 2; ++mt)
        #pragma unroll
        for (int nt = 0; nt < 2; ++nt)
          acc[mt][nt] = __builtin_amdgcn_mfma_f32_16x16x32_bf16(xfrag[j][mt], wih[nt][j], acc[mt][nt], 0, 0, 0);

    if (t > 0) {
      const unsigned short* Aprev = slab + (size_t)(t - t0) * (BATCH * HDIM);
      // stage 32x1024 h slab via system-scope 8B loads (LLC-coherent)
      #pragma unroll
      for (int p = 0; p < 16; ++p) {
        int idx = p * 256 + tid;
        int row = idx >> 7, gc = idx & 127;
        const unsigned short* src = Aprev + (size_t)(r0 + row) * HDIM + gc * 8;
        unsigned long long q0 = ld_sys_u64(src);
        unsigned long long q1 = ld_sys_u64(src + 4);
        unsigned long long* dst = (unsigned long long*)((char*)As + row * AS_STRIDE + gc * 16);
        dst[0] = q0; dst[1] = q1;
      }
      __syncthreads();
      #pragma unroll
      for (int j = 0; j < 32; ++j) {
        bf16x8 af[2];
        #pragma unroll
        for (int mt = 0; mt < 2; ++mt)
          af[mt] = *(const bf16x8*)((const char*)As + (mt * 16 + (lane & 15)) * AS_STRIDE + j * 64 + quad * 16);
        #pragma unroll
        for (int mt = 0; mt < 2; ++mt)
          #pragma unroll
          for (int nt = 0; nt < 2; ++nt)
            acc[mt][nt] = __builtin_amdgcn_mfma_f32_16x16x32_bf16(af[mt], whh[nt][j], acc[mt][nt], 0, 0, 0);
      }
    }

    __syncthreads();
    #pragma unroll
    for (int mt = 0; mt < 2; ++mt)
      #pragma unroll
      for (int nt = 0; nt < 2; ++nt) {
        int hl = nt * 16 + (lane & 15);
        int rq = mt * 16 + quad * 4;
        *(f32x4*)&gbuf[wv][hl][rq] = acc[mt][nt];
      }
    __syncthreads();

    unsigned short* hdst = slab + (size_t)(t - t0 + 1) * (BATCH * HDIM);
    unsigned short* hdst0 = slab;
    #pragma unroll
    for (int rr = 0; rr < 2; ++rr) {
      int row = rr2 + rr;
      unsigned int pack;
      unsigned short* ph = (unsigned short*)&pack;
      #pragma unroll
      for (int cc = 0; cc < 2; ++cc) {
        float gi = gbuf[0][c2 + cc][row] + bias[0][cc];
        float gf = gbuf[1][c2 + cc][row] + bias[1][cc];
        float gg = gbuf[2][c2 + cc][row] + bias[2][cc];
        float go = gbuf[3][c2 + cc][row] + bias[3][cc];
        float iv = sigm(gi), fv = sigm(gf), gv = tanh_f(gg), ov = sigm(go);
        float cn = fv * c[rr][cc] + iv * gv;
        c[rr][cc] = cn;
        float hv = ov * tanh_f(cn);
        ph[cc] = f2bf(hv);
        size_t gidx = (size_t)(r0 + row) * HDIM + hc0 + c2 + cc;
        if (t == tend - 1) cstate[gidx] = cn;
        if (t == T_STEPS - 1) { dout_h[gidx] = hv; dout_c[gidx] = cn; }
      }
      size_t goff = (size_t)(r0 + row) * HDIM + hc0 + c2;
      st_sys_u32(hdst + goff, pack);
      if (t == tend - 1) *(unsigned int*)(hdst0 + goff) = pack;
    }

    if (t != tend - 1) {
      // prefetch x fragments for t+1 before waiting
      #pragma unroll
      for (int j = 0; j < 4; ++j)
        #pragma unroll
        for (int mt = 0; mt < 2; ++mt)
          xfrag[j][mt] = *(const bf16x8*)(xbf + (size_t)((t + 1) * BATCH + r0 + mt * 16 + (lane & 15)) * FDIM + j * 32 + quad * 8);
      grp_barrier(gbar, gen_base + 1u + (unsigned int)(t - t0));
    }
  }
}

// --------------------------- layer 1: persistent chunk ----------------------
__global__ __launch_bounds__(256, 1) void lstm_layer1_kernel(
    const unsigned short* __restrict__ xw,   // (ch_len, 4096, 256)
    const float* __restrict__ Whh,
    const float* __restrict__ bih,
    const float* __restrict__ bhh,
    unsigned short* __restrict__ hpp,        // 2-slot ping-pong
    float* __restrict__ cstate,
    int t0, int ch_len, unsigned int gen_base,
    unsigned short* __restrict__ h1t0,
    float* __restrict__ dout_h,
    float* __restrict__ dout_c,
    unsigned int* __restrict__ bar)
{
  const int tid = threadIdx.x, lane = tid & 63, wv = tid >> 6;
  const int quad = lane >> 4;
  const int wg = blockIdx.x;
  const int mi = wg & 7, ni = wg >> 3;
  const int r0 = mi * 32, hc0 = ni * 32;
  unsigned int* gbar = bar + mi * 128;

  __shared__ unsigned short As[32 * (AS_STRIDE / 2)];
  __shared__ float gbuf[4][32][36];

  bf16x8 whh[2][32];
  #pragma unroll
  for (int nt = 0; nt < 2; ++nt) {
    const float* wrow = Whh + (size_t)(wv * HDIM + hc0 + nt * 16 + (lane & 15)) * HDIM + quad * 8;
    #pragma unroll
    for (int kk = 0; kk < 32; ++kk) {
      f32x4 f0 = *(const f32x4*)(wrow + kk * 32);
      f32x4 f1 = *(const f32x4*)(wrow + kk * 32 + 4);
      bf16x8 r;
      r[0] = (__bf16)f0[0]; r[1] = (__bf16)f0[1]; r[2] = (__bf16)f0[2]; r[3] = (__bf16)f0[3];
      r[4] = (__bf16)f1[0]; r[5] = (__bf16)f1[1]; r[6] = (__bf16)f1[2]; r[7] = (__bf16)f1[3];
      whh[nt][kk] = r;
    }
  }

  const int c2 = (tid & 15) * 2, rr2 = (tid >> 4) * 2;
  float bias[4][2];
  #pragma unroll
  for (int g = 0; g < 4; ++g)
    #pragma unroll
    for (int cc = 0; cc < 2; ++cc)
      bias[g][cc] = bih[g * HDIM + hc0 + c2 + cc] + bhh[g * HDIM + hc0 + c2 + cc];

  float c[2][2];
  #pragma unroll
  for (int rr = 0; rr < 2; ++rr)
    #pragma unroll
    for (int cc = 0; cc < 2; ++cc)
      c[rr][cc] = (t0 == 0) ? 0.f
                : cstate[(size_t)(r0 + rr2 + rr) * HDIM + hc0 + c2 + cc];

  // prefetch xw for first step: [gate][col 0/1] -> u32 = rows {r2, r2+1}
  unsigned int xwp[4][2];
  #pragma unroll
  for (int g = 0; g < 4; ++g)
    #pragma unroll
    for (int cc = 0; cc < 2; ++cc)
      xwp[g][cc] = *(const unsigned int*)(xw + ((size_t)0 * GDIM + g * HDIM + hc0 + c2 + cc) * BATCH + r0 + rr2);

  const int tend = t0 + ch_len;
  #pragma unroll 1
  for (int t = t0; t < tend; ++t) {
    f32x4 acc[2][2];
    #pragma unroll
    for (int mt = 0; mt < 2; ++mt)
      #pragma unroll
      for (int nt = 0; nt < 2; ++nt) acc[mt][nt] = f32x4{0.f, 0.f, 0.f, 0.f};

    if (t > 0) {
      const unsigned short* Aprev = hpp + (size_t)((t - 1) & 1) * (BATCH * HDIM);
      #pragma unroll
      for (int p = 0; p < 16; ++p) {
        int idx = p * 256 + tid;
        int row = idx >> 7, gc = idx & 127;
        const unsigned short* src = Aprev + (size_t)(r0 + row) * HDIM + gc * 8;
        unsigned long long q0 = ld_sys_u64(src);
        unsigned long long q1 = ld_sys_u64(src + 4);
        unsigned long long* dst = (unsigned long long*)((char*)As + row * AS_STRIDE + gc * 16);
        dst[0] = q0; dst[1] = q1;
      }
      __syncthreads();
      #pragma unroll
      for (int j = 0; j < 32; ++j) {
        bf16x8 af[2];
        #pragma unroll
        for (int mt = 0; mt < 2; ++mt)
          af[mt] = *(const bf16x8*)((const char*)As + (mt * 16 + (lane & 15)) * AS_STRIDE + j * 64 + quad * 16);
        #pragma unroll
        for (int mt = 0; mt < 2; ++mt)
          #pragma unroll
          for (int nt = 0; nt < 2; ++nt)
            acc[mt][nt] = __builtin_amdgcn_mfma_f32_16x16x32_bf16(af[mt], whh[nt][j], acc[mt][nt], 0, 0, 0);
      }
    }

    __syncthreads();
    #pragma unroll
    for (int mt = 0; mt < 2; ++mt)
      #pragma unroll
      for (int nt = 0; nt < 2; ++nt) {
        int hl = nt * 16 + (lane & 15);
        int rq = mt * 16 + quad * 4;
        *(f32x4*)&gbuf[wv][hl][rq] = acc[mt][nt];
      }
    __syncthreads();

    unsigned short* hdst = hpp + (size_t)(t & 1) * (BATCH * HDIM);
    #pragma unroll
    for (int rr = 0; rr < 2; ++rr) {
      int row = rr2 + rr;
      unsigned int pack;
      unsigned short* ph = (unsigned short*)&pack;
      #pragma unroll
      for (int cc = 0; cc < 2; ++cc) {
        const unsigned short* xv = (const unsigned short*)&xwp[0][0];
        float gi = gbuf[0][c2 + cc][row] + bf2f(((unsigned short*)&xwp[0][cc])[rr]) + bias[0][cc];
        float gf = gbuf[1][c2 + cc][row] + bf2f(((unsigned short*)&xwp[1][cc])[rr]) + bias[1][cc];
        float gg = gbuf[2][c2 + cc][row] + bf2f(((unsigned short*)&xwp[2][cc])[rr]) + bias[2][cc];
        float go = gbuf[3][c2 + cc][row] + bf2f(((unsigned short*)&xwp[3][cc])[rr]) + bias[3][cc];
        (void)xv;
        float iv = sigm(gi), fv = sigm(gf), gv = tanh_f(gg), ov = sigm(go);
        float cn = fv * c[rr][cc] + iv * gv;
        c[rr][cc] = cn;
        float hv = ov * tanh_f(cn);
        ph[cc] = f2bf(hv);
        size_t gidx = (size_t)(r0 + row) * HDIM + hc0 + c2 + cc;
        if (t == tend - 1) cstate[gidx] = cn;
        if (t == T_STEPS - 1) { dout_h[gidx] = hv; dout_c[gidx] = cn; }
      }
      size_t goff = (size_t)(r0 + row) * HDIM + hc0 + c2;
      st_sys_u32(hdst + goff, pack);
      if (h1t0 != nullptr && t == 0) *(unsigned int*)(h1t0 + goff) = pack;
    }

    if (t != tend - 1) {
      // prefetch next step's xw before waiting
      #pragma unroll
      for (int g = 0; g < 4; ++g)
        #pragma unroll
        for (int cc = 0; cc < 2; ++cc)
          xwp[g][cc] = *(const unsigned int*)(xw + ((size_t)(t + 1 - t0) * GDIM + g * HDIM + hc0 + c2 + cc) * BATCH + r0 + rr2);
      grp_barrier(gbar, gen_base + 1u + (unsigned int)(t - t0));
    }
  }
}

__global__ void y_kernel(const unsigned short* __restrict__ h1t0,
                         const unsigned short* __restrict__ wlin,
                         const float* __restrict__ blin,
                         float* __restrict__ y)
{
  int b = blockIdx.x;
  int f = threadIdx.x;
  const ushort8v* hp = (const ushort8v*)(h1t0 + (size_t)b * HDIM);
  const ushort8v* wp = (const ushort8v*)(wlin + (size_t)f * HDIM);
  float acc = 0.f;
  for (int i = 0; i < HDIM / 8; ++i) {
    ushort8v hv = hp[i], wvv = wp[i];
    #pragma unroll
    for (int j = 0; j < 8; ++j) acc += bf2f(hv[j]) * bf2f(wvv[j]);
  }
  y[b * FDIM + f] = acc + blin[f];
}

// ---------------------------------------------------------------------------
extern "C" void kernel_launch(void* const* d_in, const int* in_sizes, int n_in,
                              void* d_out, int out_size, void* d_ws, size_t ws_size,
                              hipStream_t stream) {
  (void)in_sizes; (void)n_in; (void)out_size;
  const float* x    = (const float*)d_in[0];
  const float* Wih0 = (const float*)d_in[1];
  const float* Whh0 = (const float*)d_in[2];
  const float* bih0 = (const float*)d_in[3];
  const float* bhh0 = (const float*)d_in[4];
  const float* Wih1 = (const float*)d_in[5];
  const float* Whh1 = (const float*)d_in[6];
  const float* bih1 = (const float*)d_in[7];
  const float* bhh1 = (const float*)d_in[8];
  const float* Wlin = (const float*)d_in[9];
  const float* blin = (const float*)d_in[10];
  float* out = (float*)d_out;

  const size_t SZ_BAR   = 8192;
  const size_t SZ_XBF   = (size_t)T_STEPS * BATCH * FDIM * 2;
  const size_t SZ_WIH1  = (size_t)GDIM * HDIM * 2;
  const size_t SZ_WLIN  = (size_t)FDIM * HDIM * 2;
  const size_t SZ_HPP   = (size_t)2 * BATCH * HDIM * 2;
  const size_t SZ_H1T0  = (size_t)BATCH * HDIM * 2;
  const size_t SZ_CST   = (size_t)BATCH * HDIM * 4;
  const size_t SLOT     = (size_t)BATCH * HDIM * 2;
  const size_t fixed = SZ_BAR + SZ_XBF + SZ_WIH1 + SZ_WLIN + SZ_HPP + SZ_H1T0 + 2 * SZ_CST;

  int CH = 0;
  const int cands[5] = {64, 32, 16, 8, 4};
  for (int i = 0; i < 5; ++i) {
    int c = cands[i];
    size_t need = fixed + (size_t)(c + 1) * SLOT + (size_t)c * GDIM * BATCH * 2;
    if (need <= ws_size) { CH = c; break; }
  }
  if (CH == 0) {
    float v = 1.0e6f + (float)(ws_size >> 20);
    diag_kernel<<<(32768 + 255) / 256, 256, 0, stream>>>(out, 32768, v);
    return;
  }

  char* ws = (char*)d_ws;
  size_t o = 0;
  unsigned int*   bar   = (unsigned int*)(ws + o);    o += SZ_BAR;
  unsigned short* xbf   = (unsigned short*)(ws + o);  o += SZ_XBF;
  unsigned short* wih1b = (unsigned short*)(ws + o);  o += SZ_WIH1;
  unsigned short* wlinb = (unsigned short*)(ws + o);  o += SZ_WLIN;
  unsigned short* h1pp  = (unsigned short*)(ws + o);  o += SZ_HPP;
  unsigned short* h1t0  = (unsigned short*)(ws + o);  o += SZ_H1T0;
  float*          c0st  = (float*)(ws + o);           o += SZ_CST;
  float*          c1st  = (float*)(ws + o);           o += SZ_CST;
  unsigned short* slab  = (unsigned short*)(ws + o);  o += (size_t)(CH + 1) * SLOT;
  unsigned short* xw1   = (unsigned short*)(ws + o);  o += (size_t)CH * GDIM * BATCH * 2;

  hipMemsetAsync(bar, 0, SZ_BAR, stream);

  conv_bf16<<<(T_STEPS * BATCH * FDIM + 255) / 256, 256, 0, stream>>>(x, xbf, T_STEPS * BATCH * FDIM);
  conv_bf16<<<(GDIM * HDIM + 255) / 256, 256, 0, stream>>>(Wih1, wih1b, GDIM * HDIM);
  conv_bf16<<<(FDIM * HDIM + 255) / 256, 256, 0, stream>>>(Wlin, wlinb, FDIM * HDIM);

  float* hn0 = out + 32768;
  float* hn1 = out + 32768 + 262144;
  float* cn0 = out + 32768 + 524288;
  float* cn1 = out + 32768 + 524288 + 262144;

  unsigned int gen_base = 0;
  for (int ch = 0; ch < T_STEPS / CH; ++ch) {
    int t0 = ch * CH;
    lstm_layer0_kernel<<<256, 256, 0, stream>>>(
        xbf, Wih0, Whh0, bih0, bhh0, slab, c0st, t0, CH, gen_base, hn0, cn0, bar);
    gen_base += (unsigned int)(CH - 1);
    gemm_bt_xw<<<dim3(CH * 2, 32), 256, 0, stream>>>(
        slab + BATCH * HDIM, wih1b, xw1, HDIM);
    lstm_layer1_kernel<<<256, 256, 0, stream>>>(
        xw1, Whh1, bih1, bhh1, h1pp, c1st, t0, CH, gen_base, h1t0, hn1, cn1, bar);
    gen_base += (unsigned int)(CH - 1);
  }

  y_kernel<<<256, 128, 0, stream>>>(h1t0, wlinb, blin, out);
}